// Round 8
// baseline (1266.342 us; speedup 1.0000x reference)
//
#include <hip/hip_runtime.h>
#include <math.h>

#define NB 10
#define PPC 29          // 3*NB-1
#define CCH 4
#define HID 64
#define HH 256
#define WW 256
#define BB 16
#define TB 1.0f
#define MINW 0.001f
#define MINH 0.001f
#define MIND 0.001f

#define ZTOT (BB*CCH*HH*WW)     // 4194304

// Tile: 8x8 pixels. M=64, N=128 (116 valid), K=576. 16384 blocks.
#define HALO_PIX 100            // 10 x 10
// s_hid: 100 rows x 64 shorts (128 B), XOR-swizzled 16B chunks: no pad needed.
// chunk_in_row = (ks*4+quad) ^ (row&7). Per-quad rows cover each mod-8 residue
// exactly 2x -> every chunk column hit exactly 2 lanes (free) -> zero surplus conflicts.
#define PSTR 117                // p_buf row stride (f32): odd -> conflict-free spline reads
#define NCOLS 116               // valid N columns; >=116 is zero-padding (never stored)
#define W2B_ELEMS (18*8*64*8)   // 73728 bf16 per copy; hi+lo = 294912 B in d_ws

typedef __attribute__((ext_vector_type(8))) short short8v;
typedef __attribute__((ext_vector_type(4))) float f32x4;

__device__ inline unsigned short f2bf(float f) {
    unsigned u = __float_as_uint(f);
    unsigned r = (u + 0x7FFFu + ((u >> 16) & 1u)) >> 16;
    return (unsigned short)r;
}
__device__ inline float bf2f(unsigned short s) {
    return __uint_as_float(((unsigned)s) << 16);
}

__global__ void zero_lad_kernel(float* out) {
    out[ZTOT + threadIdx.x] = 0.0f;
}

// Prepack W2 -> bf16 fragment order, hi/lo split for ~fp32 effective precision.
// w2b[copy(2)][kidx(18)][ntile(8)][lane(64)][j(8)]
// kidx = tap*2 + ks; n = ntile*16 + (lane&15); ci = ks*32 + (lane>>4)*8 + j
__global__ void prepack_w2(const float* __restrict__ W2, unsigned short* __restrict__ w2b) {
    int idx = blockIdx.x * 256 + threadIdx.x;
    if (idx >= W2B_ELEMS) return;
    int j    = idx & 7;
    int lane = (idx >> 3) & 63;
    int nt   = (idx >> 9) & 7;
    int kidx = idx >> 12;            // 0..17
    int tap  = kidx >> 1;
    int ks   = kidx & 1;
    int ky   = tap / 3;
    int kx   = tap - ky * 3;
    int n    = nt * 16 + (lane & 15);
    int ci   = ks * 32 + (lane >> 4) * 8 + j;
    float v = 0.0f;
    if (n < PPC * CCH) v = W2[((n * HID + ci) * 3 + ky) * 3 + kx];
    unsigned short hi = f2bf(v);
    float rem = v - bf2f(hi);
    w2b[idx]             = hi;
    w2b[idx + W2B_ELEMS] = f2bf(rem);
}

__global__ __launch_bounds__(256, 5)
void fused_kernel(const float* __restrict__ x, const float* __restrict__ clean,
                  const float* __restrict__ W1, const float* __restrict__ b1,
                  const float* __restrict__ b2, const unsigned short* __restrict__ w2b,
                  float* __restrict__ out)
{
    // Union region (29952 B = 64*PSTR f32):
    //   phases A-C: s_hid = 100 x 64 bf16 swizzled (12800 B) at word 0,
    //               s_clean = 4ch*12*12 f32 (2304 B) at word 3200.
    //   epilogue:   p_buf = 64 x PSTR f32 (overwrites both, barrier-ordered).
    __shared__ __align__(16) float s_un[64 * PSTR];
    __shared__ float s_red[4];

    unsigned short* s_hid   = (unsigned short*)s_un;
    float*          s_clean = s_un + 3200;

    const int tid  = threadIdx.x;
    const int blk  = blockIdx.x;
    const int b    = blk >> 10;
    const int ty   = (blk >> 5) & 31;
    const int tx   = blk & 31;
    const int Y0 = ty * 8, X0 = tx * 8;

    const int w    = tid >> 6;        // wave id == spline channel c == N-quarter
    const int lane = tid & 63;
    const int l15  = lane & 15;
    const int quad = lane >> 4;

    // Prefetch x early so the tail load isn't barrier-exposed.
    const int spy = lane >> 3, spx = lane & 7;
    const int gidx = ((b*CCH + w) << 16) + (Y0 + spy)*WW + (X0 + spx);
    const float xv = x[gidx];

    // ---------- Phase A: stage clean tile (4ch x 12 x 12, zero-padded) ----------
    for (int i = tid; i < CCH*12*12; i += 256) {
        int c  = i / 144;
        int r  = i - c * 144;
        int cy = r / 12;
        int cx = r - cy * 12;
        int iy = Y0 - 2 + cy, ix = X0 - 2 + cx;
        float v = 0.0f;
        if (iy >= 0 && iy < HH && ix >= 0 && ix < WW)
            v = clean[((b*CCH + c) << 16) + iy*WW + ix];
        s_clean[i] = v;
    }
    __syncthreads();

    // ---------- Phase B: hid = relu(conv1(clean)) on 10x10 halo -> s_hid bf16 ----------
    // All 4 waves: wave w computes co in [16w, 16w+16) for every halo pixel.
    // co stays WAVE-UNIFORM -> W1 reads are scalar s_loads (R6 regression lesson).
    for (int pass = 0; pass < 2; ++pass) {
        int pix = pass * 64 + lane;
        if (pix < HALO_PIX) {
            int hy = pix / 10, hx = pix - hy * 10;
            int iy = Y0 - 1 + hy, ix = X0 - 1 + hx;
            bool valid = (iy >= 0 && iy < HH && ix >= 0 && ix < WW);
            float cwin[36];
            #pragma unroll
            for (int c = 0; c < 4; ++c)
                #pragma unroll
                for (int ky = 0; ky < 3; ++ky)
                    #pragma unroll
                    for (int kx = 0; kx < 3; ++kx)
                        cwin[c*9 + ky*3 + kx] = s_clean[c*144 + (hy+ky)*12 + (hx+kx)];
            int swz = (pix & 7) << 3;
            #pragma unroll
            for (int cog = 0; cog < 2; ++cog) {
                float a8[8];
                #pragma unroll
                for (int coi = 0; coi < 8; ++coi) {
                    int co = w*16 + cog*8 + coi;                 // wave-uniform
                    const float4* wv = (const float4*)(W1 + co*36);  // -> s_load
                    float a = b1[co];
                    #pragma unroll
                    for (int q = 0; q < 9; ++q) {
                        float4 t4 = wv[q];
                        a += t4.x*cwin[q*4] + t4.y*cwin[q*4+1] + t4.z*cwin[q*4+2] + t4.w*cwin[q*4+3];
                    }
                    a8[coi] = valid ? fmaxf(a, 0.0f) : 0.0f;
                }
                uint4 pk;
                pk.x = (unsigned)f2bf(a8[0]) | ((unsigned)f2bf(a8[1]) << 16);
                pk.y = (unsigned)f2bf(a8[2]) | ((unsigned)f2bf(a8[3]) << 16);
                pk.z = (unsigned)f2bf(a8[4]) | ((unsigned)f2bf(a8[5]) << 16);
                pk.w = (unsigned)f2bf(a8[6]) | ((unsigned)f2bf(a8[7]) << 16);
                int chunk = (w*2 + cog) << 3;                    // co>>3, in shorts
                *(uint4*)(&s_hid[(pix << 6) + (chunk ^ swz)]) = pk;  // 16B-aligned
            }
        }
    }
    __syncthreads();

    // ---------- Phase C: conv2 as implicit GEMM via MFMA (B = W2_hi + W2_lo) ----------
    // Wave w: ntiles {2w, 2w+1} x all 4 mtiles = 8 acc tiles (32 f32/thread).
    // B-fragments are prefetched one full k-step ahead (software pipeline).
    f32x4 acc[4][2];
    #pragma unroll
    for (int mi = 0; mi < 4; ++mi)
        #pragma unroll
        for (int t = 0; t < 2; ++t) {
            acc[mi][t][0] = 0.f; acc[mi][t][1] = 0.f;
            acc[mi][t][2] = 0.f; acc[mi][t][3] = 0.f;
        }

    const short8v* __restrict__ wbv_hi = (const short8v*)w2b;
    const short8v* __restrict__ wbv_lo = (const short8v*)(w2b + W2B_ELEMS);

    // A-row mapping: pixel p = mi*16 + l15; py = mi*2 + (l15>>3), px = l15&7.
    const int px8 = l15 & 7;
    const int pyb = l15 >> 3;

    int bo0 = (w*2)*64 + lane;
    short8v nh0 = wbv_hi[bo0], nh1 = wbv_hi[bo0 + 64];
    short8v nl0 = wbv_lo[bo0], nl1 = wbv_lo[bo0 + 64];

    for (int tap = 0; tap < 9; ++tap) {
        int ky = tap / 3;
        int kx = tap - ky * 3;
        int rb[4], rs[4];
        #pragma unroll
        for (int mi = 0; mi < 4; ++mi) {
            int row = (mi*2 + pyb + ky)*10 + px8 + kx;
            rb[mi] = row << 6;            // row base in shorts
            rs[mi] = (row & 7) << 3;      // swizzle key in shorts
        }
        #pragma unroll
        for (int ks = 0; ks < 2; ++ks) {
            short8v bh0 = nh0, bh1 = nh1, bl0 = nl0, bl1 = nl1;
            int kidx = tap*2 + ks;
            if (kidx < 17) {
                int bo = ((kidx + 1)*8 + w*2)*64 + lane;
                nh0 = wbv_hi[bo]; nh1 = wbv_hi[bo + 64];
                nl0 = wbv_lo[bo]; nl1 = wbv_lo[bo + 64];
            }
            short8v afr[4];
            #pragma unroll
            for (int mi = 0; mi < 4; ++mi) {
                int ch = (((ks << 2) + quad) << 3) ^ rs[mi];
                afr[mi] = *(const short8v*)(s_hid + rb[mi] + ch);   // ds_read_b128, swizzled
            }
            #pragma unroll
            for (int mi = 0; mi < 4; ++mi) {
                acc[mi][0] = __builtin_amdgcn_mfma_f32_16x16x32_bf16(afr[mi], bh0, acc[mi][0], 0, 0, 0);
                acc[mi][1] = __builtin_amdgcn_mfma_f32_16x16x32_bf16(afr[mi], bh1, acc[mi][1], 0, 0, 0);
            }
            #pragma unroll
            for (int mi = 0; mi < 4; ++mi) {
                acc[mi][0] = __builtin_amdgcn_mfma_f32_16x16x32_bf16(afr[mi], bl0, acc[mi][0], 0, 0, 0);
                acc[mi][1] = __builtin_amdgcn_mfma_f32_16x16x32_bf16(afr[mi], bl1, acc[mi][1], 0, 0, 0);
            }
        }
    }

    // ---------- Epilogue: all acc -> p_buf (aliases s_hid/s_clean), then spline ----------
    float* p_buf = s_un;
    const float* b2c = b2 + w * PPC;      // wave-uniform -> scalar loads

    __syncthreads();   // all s_hid MFMA reads complete before p_buf overwrites
    #pragma unroll
    for (int mi = 0; mi < 4; ++mi) {
        #pragma unroll
        for (int t = 0; t < 2; ++t) {
            int col = (w*2 + t)*16 + l15;
            if (col < NCOLS) {    // cols >=116 are padding; would wrap PSTR (R3 bug)
                f32x4 v = acc[mi][t];
                int base = (mi*16 + quad*4) * PSTR + col;
                p_buf[base]          = v[0];
                p_buf[base + PSTR]   = v[1];
                p_buf[base + 2*PSTR] = v[2];
                p_buf[base + 3*PSTR] = v[3];
            }
        }
    }
    __syncthreads();

    // spline: thread -> (c = w, pixel = lane); all 256 threads active, single pass
    float pv[PPC];
    #pragma unroll
    for (int j = 0; j < PPC; ++j)
        pv[j] = p_buf[lane * PSTR + w * PPC + j];

    const float scale = 0.125f;   // 1/sqrt(HIDDEN)
    float uw[NB], uh[NB], ud9[NB-1];
    #pragma unroll
    for (int j = 0; j < NB; ++j)   uw[j]  = (pv[j]      + b2c[j])      * scale;
    #pragma unroll
    for (int j = 0; j < NB; ++j)   uh[j]  = (pv[NB+j]   + b2c[NB+j])   * scale;
    #pragma unroll
    for (int j = 0; j < NB-1; ++j) ud9[j] =  pv[2*NB+j] + b2c[2*NB+j];

    float mw = uw[0];
    #pragma unroll
    for (int j = 1; j < NB; ++j) mw = fmaxf(mw, uw[j]);
    float sw = 0.0f;
    #pragma unroll
    for (int j = 0; j < NB; ++j) { uw[j] = __expf(uw[j] - mw); sw += uw[j]; }
    float isw = 1.0f / sw;
    float cw[NB+1];
    cw[0] = -TB;
    float run = 0.0f;
    #pragma unroll
    for (int j = 0; j < NB; ++j) {
        float wj = MINW + (1.0f - MINW*NB) * (uw[j] * isw);
        run += wj;
        cw[j+1] = -TB + 2.0f*TB*run;
    }
    cw[NB] = TB;

    float mh = uh[0];
    #pragma unroll
    for (int j = 1; j < NB; ++j) mh = fmaxf(mh, uh[j]);
    float sh = 0.0f;
    #pragma unroll
    for (int j = 0; j < NB; ++j) { uh[j] = __expf(uh[j] - mh); sh += uh[j]; }
    float ish = 1.0f / sh;
    float chh[NB+1];
    chh[0] = -TB;
    float runh = 0.0f;
    #pragma unroll
    for (int j = 0; j < NB; ++j) {
        float hj = MINH + (1.0f - MINH*NB) * (uh[j] * ish);
        runh += hj;
        chh[j+1] = -TB + 2.0f*TB*runh;
    }
    chh[NB] = TB;

    float dv[NB+1];
    dv[0] = 1.0f; dv[NB] = 1.0f;
    #pragma unroll
    for (int k = 0; k < NB-1; ++k) {
        float v = ud9[k];
        // softplus via fast intrinsics: exp(-|v|) tiny -> 1+t rounds to 1 -> log 0,
        // matching the log1p asymptote
        float sp = fmaxf(v, 0.0f) + __logf(1.0f + __expf(-fabsf(v)));
        dv[k+1] = MIND + sp;
    }

    float xin = fminf(fmaxf(xv, -TB), TB);
    int cnt = 0;
    #pragma unroll
    for (int k = 0; k <= NB; ++k) cnt += (xin >= cw[k]) ? 1 : 0;
    int idx = cnt - 1;
    idx = idx < 0 ? 0 : (idx > NB-1 ? NB-1 : idx);

    float icw = cw[0], inw = cw[1], ich = chh[0], inh = chh[1], d0 = dv[0], d1 = dv[1];
    #pragma unroll
    for (int k = 1; k < NB; ++k) {
        bool m = (idx == k);
        icw = m ? cw[k]    : icw;
        inw = m ? cw[k+1]  : inw;
        ich = m ? chh[k]   : ich;
        inh = m ? chh[k+1] : inh;
        d0  = m ? dv[k]    : d0;
        d1  = m ? dv[k+1]  : d1;
    }
    float ibw = inw - icw;
    float ihh = inh - ich;
    float idl = ihh / ibw;
    float th  = (xin - icw) / ibw;
    float omt = 1.0f - th;
    float tt  = th * omt;
    float numer = ihh * (idl*th*th + d0*tt);
    float den   = idl + (d0 + d1 - 2.0f*idl)*tt;
    float z_in  = ich + numer/den;
    float dnum  = idl*idl*(d1*th*th + 2.0f*idl*tt + d0*omt*omt);
    float lad_in = __logf(dnum) - 2.0f*__logf(den);
    bool inside = (xv >= -TB) && (xv <= TB);
    float z = inside ? z_in : xv;
    float lad = inside ? lad_in : 0.0f;
    out[gidx] = z;

    // ---------- block-reduce lad, one atomic per block ----------
    #pragma unroll
    for (int off = 32; off >= 1; off >>= 1)
        lad += __shfl_xor(lad, off, 64);
    if (lane == 0) s_red[w] = lad;
    __syncthreads();
    if (tid == 0)
        atomicAdd(out + ZTOT + b, s_red[0] + s_red[1] + s_red[2] + s_red[3]);
}

extern "C" void kernel_launch(void* const* d_in, const int* in_sizes, int n_in,
                              void* d_out, int out_size, void* d_ws, size_t ws_size,
                              hipStream_t stream) {
    const float* x     = (const float*)d_in[0];
    const float* clean = (const float*)d_in[1];
    const float* W1    = (const float*)d_in[2];
    const float* b1    = (const float*)d_in[3];
    const float* W2    = (const float*)d_in[4];
    const float* b2    = (const float*)d_in[5];
    float* out = (float*)d_out;
    unsigned short* w2b = (unsigned short*)d_ws;   // 294912 B (hi + lo copies)

    zero_lad_kernel<<<1, 16, 0, stream>>>(out);
    prepack_w2<<<(W2B_ELEMS + 255)/256, 256, 0, stream>>>(W2, w2b);
    fused_kernel<<<BB*32*32, 256, 0, stream>>>(x, clean, W1, b1, b2, w2b, out);
}

// Round 9
// 638.288 us; speedup vs baseline: 1.9840x; 1.9840x over previous
//
#include <hip/hip_runtime.h>
#include <math.h>

#define NB 10
#define PPC 29          // 3*NB-1
#define CCH 4
#define HID 64
#define HH 256
#define WW 256
#define BB 16
#define TB 1.0f
#define MINW 0.001f
#define MINH 0.001f
#define MIND 0.001f

#define ZTOT (BB*CCH*HH*WW)     // 4194304

// Tile: 8x8 pixels. M=64, N=128 (116 valid), K=576. 16384 blocks.
#define HALO_PIX 100            // 10 x 10
#define PSTR 117                // p_buf row stride (f32): odd -> conflict-free spline reads
#define NCOLS 116               // valid N columns; >=116 is zero-padding (never stored)
#define W2B_ELEMS (18*8*64*8)   // 73728 bf16 per copy; hi+lo = 294912 B
#define W1B_ELEMS 4096          // per copy: [ks(2)][nt(4)][lane(64)][j(8)]; hi+lo = 16384 B

// LDS word map inside the 64*PSTR f32 union:
//   A_tile  words    0..3583  (112 rows x 32 words, bf16 im2col, swizzled)
//   s_hid   words 3584..6783  (100 rows x 32 words, bf16, swizzled)
//   s_clean words 6784..7359  (4ch x 12 x 12 f32)
//   p_buf   words    0..7487  (epilogue, overwrites all, barrier-ordered)

typedef __attribute__((ext_vector_type(8))) short short8v;
typedef __attribute__((ext_vector_type(4))) float f32x4;

__device__ inline unsigned short f2bf(float f) {
    unsigned u = __float_as_uint(f);
    unsigned r = (u + 0x7FFFu + ((u >> 16) & 1u)) >> 16;
    return (unsigned short)r;
}
__device__ inline float bf2f(unsigned short s) {
    return __uint_as_float(((unsigned)s) << 16);
}

__global__ void zero_lad_kernel(float* out) {
    out[ZTOT + threadIdx.x] = 0.0f;
}

// Prepack W2 (hi/lo) and W1 (hi/lo) into MFMA B-fragment order.
// W2: w2b[copy(2)][kidx(18)][ntile(8)][lane(64)][j(8)]; kidx=tap*2+ks,
//     n=ntile*16+(lane&15), ci=ks*32+(lane>>4)*8+j.
// W1: w1b[copy(2)][ks(2)][nt(4)][lane(64)][j(8)]; co=nt*16+(lane&15),
//     k=ks*32+(lane>>4)*8+j; W1 flat index = co*36+k (k<36), else 0.
__global__ void prepack_w(const float* __restrict__ W2, const float* __restrict__ W1,
                          unsigned short* __restrict__ wb) {
    int idx = blockIdx.x * 256 + threadIdx.x;
    if (idx < W2B_ELEMS) {
        int j    = idx & 7;
        int lane = (idx >> 3) & 63;
        int nt   = (idx >> 9) & 7;
        int kidx = idx >> 12;            // 0..17
        int tap  = kidx >> 1;
        int ks   = kidx & 1;
        int ky   = tap / 3;
        int kx   = tap - ky * 3;
        int n    = nt * 16 + (lane & 15);
        int ci   = ks * 32 + (lane >> 4) * 8 + j;
        float v = 0.0f;
        if (n < PPC * CCH) v = W2[((n * HID + ci) * 3 + ky) * 3 + kx];
        unsigned short hi = f2bf(v);
        wb[idx]             = hi;
        wb[idx + W2B_ELEMS] = f2bf(v - bf2f(hi));
    } else if (idx < W2B_ELEMS + W1B_ELEMS) {
        int e    = idx - W2B_ELEMS;
        int j    = e & 7;
        int lane = (e >> 3) & 63;
        int nt   = (e >> 9) & 3;
        int ks   = (e >> 11) & 1;
        int co   = nt * 16 + (lane & 15);
        int k    = ks * 32 + (lane >> 4) * 8 + j;
        float v = (k < 36) ? W1[co * 36 + k] : 0.0f;
        unsigned short hi = f2bf(v);
        wb[2*W2B_ELEMS + e]             = hi;
        wb[2*W2B_ELEMS + W1B_ELEMS + e] = f2bf(v - bf2f(hi));
    }
}

__global__ __launch_bounds__(256, 5)
void fused_kernel(const float* __restrict__ x, const float* __restrict__ clean,
                  const float* __restrict__ b1, const float* __restrict__ b2,
                  const unsigned short* __restrict__ wb, float* __restrict__ out)
{
    __shared__ __align__(16) float s_un[64 * PSTR];   // 29952 B
    __shared__ float s_red[4];

    unsigned short* A_t     = (unsigned short*)s_un;          // 112 x 64 bf16
    unsigned short* s_hid   = (unsigned short*)(s_un + 3584); // 100 x 64 bf16
    float*          s_clean = s_un + 6784;                    // 4 x 12 x 12 f32

    const int tid  = threadIdx.x;
    const int blk  = blockIdx.x;
    const int b    = blk >> 10;
    const int ty   = (blk >> 5) & 31;
    const int tx   = blk & 31;
    const int Y0 = ty * 8, X0 = tx * 8;

    const int w    = tid >> 6;        // wave id == spline channel c == conv1 ntile == conv2 N-quarter
    const int lane = tid & 63;
    const int l15  = lane & 15;
    const int quad = lane >> 4;

    // Prefetch x early so the tail load isn't barrier-exposed.
    const int spy = lane >> 3, spx = lane & 7;
    const int gidx = ((b*CCH + w) << 16) + (Y0 + spy)*WW + (X0 + spx);
    const float xv = x[gidx];

    // ---------- Phase A: stage clean tile (4ch x 12 x 12, zero-padded) ----------
    for (int i = tid; i < CCH*12*12; i += 256) {
        int c  = i / 144;
        int r  = i - c * 144;
        int cy = r / 12;
        int cx = r - cy * 12;
        int iy = Y0 - 2 + cy, ix = X0 - 2 + cx;
        float v = 0.0f;
        if (iy >= 0 && iy < HH && ix >= 0 && ix < WW)
            v = clean[((b*CCH + c) << 16) + iy*WW + ix];
        s_clean[i] = v;
    }
    __syncthreads();

    // ---------- Phase A2: build im2col A-tile (112 x 64 bf16, swizzled) ----------
    // A[m][k]: m = halo pixel (10x10 row-major, rows 100..111 are pad),
    //          k = ci*9 + ky*3 + kx for k<36, zero for k>=36.
    for (int i = tid; i < 3584; i += 256) {
        int m  = i >> 5;
        int wd = i & 31;
        int hy = m / 10, hx = m - hy * 10;
        unsigned short h2[2];
        #pragma unroll
        for (int e = 0; e < 2; ++e) {
            int k  = wd*2 + e;
            int kc = (k < 36) ? k : 0;
            int c  = kc / 9;
            int t  = kc - 9*c;
            int ky = t / 3;
            int kx = t - 3*ky;
            float v = s_clean[c*144 + (hy + ky)*12 + (hx + kx)];
            if (k >= 36 || m >= HALO_PIX) v = 0.0f;
            h2[e] = f2bf(v);
        }
        unsigned pk = (unsigned)h2[0] | ((unsigned)h2[1] << 16);
        int chunk = (wd >> 2) ^ (m & 7);
        *(unsigned*)(A_t + (m << 6) + (chunk << 3) + ((wd & 3) << 1)) = pk;
    }
    __syncthreads();

    // ---------- Phase B: conv1 via MFMA. Wave w: co in [16w,16w+16), 7 mtiles ----------
    {
        const short8v* w1v = (const short8v*)(wb + 2*W2B_ELEMS);
        // [copy][ks][nt][lane]
        short8v c1h0 = w1v[(0*4 + w)*64 + lane];          // hi ks0
        short8v c1h1 = w1v[(1*4 + w)*64 + lane];          // hi ks1
        short8v c1l0 = w1v[(2*4 + w)*64 + lane];          // lo ks0
        short8v c1l1 = w1v[(3*4 + w)*64 + lane];          // lo ks1
        float bias = b1[w*16 + l15];

        #pragma unroll
        for (int mt = 0; mt < 7; ++mt) {
            int m  = mt*16 + l15;
            int rb = m << 6;
            int rs = (m & 7) << 3;
            short8v af0 = *(const short8v*)(A_t + rb + ((quad << 3) ^ rs));        // ks0
            short8v af1 = *(const short8v*)(A_t + rb + (((4 + quad) << 3) ^ rs));  // ks1
            f32x4 a;
            a[0] = 0.f; a[1] = 0.f; a[2] = 0.f; a[3] = 0.f;
            a = __builtin_amdgcn_mfma_f32_16x16x32_bf16(af0, c1h0, a, 0, 0, 0);
            a = __builtin_amdgcn_mfma_f32_16x16x32_bf16(af1, c1h1, a, 0, 0, 0);
            a = __builtin_amdgcn_mfma_f32_16x16x32_bf16(af0, c1l0, a, 0, 0, 0);
            a = __builtin_amdgcn_mfma_f32_16x16x32_bf16(af1, c1l1, a, 0, 0, 0);
            // epilogue: hid = valid ? relu(acc + bias) : 0  -> s_hid (swizzled)
            #pragma unroll
            for (int r = 0; r < 4; ++r) {
                int p = mt*16 + quad*4 + r;
                if (p < HALO_PIX) {
                    int hy = p / 10, hx = p - hy*10;
                    int iy = Y0 - 1 + hy, ix = X0 - 1 + hx;
                    bool ok = ((unsigned)iy < HH) && ((unsigned)ix < WW);
                    float v = ok ? fmaxf(a[r] + bias, 0.0f) : 0.0f;
                    int ch = ((w*2 + (l15 >> 3)) ^ (p & 7)) << 3;
                    s_hid[(p << 6) + ch + (l15 & 7)] = f2bf(v);
                }
            }
        }
    }
    __syncthreads();

    // ---------- Phase C: conv2 implicit GEMM via MFMA (B = W2_hi + W2_lo) ----------
    // Wave w: ntiles {2w, 2w+1} x 4 mtiles = 8 acc tiles (32 f32/thread).
    // No B-prefetch: R8's +16 VGPR prefetch spilled at the (256,5) cap -> 1.75 GB scratch.
    f32x4 acc[4][2];
    #pragma unroll
    for (int mi = 0; mi < 4; ++mi)
        #pragma unroll
        for (int t = 0; t < 2; ++t) {
            acc[mi][t][0] = 0.f; acc[mi][t][1] = 0.f;
            acc[mi][t][2] = 0.f; acc[mi][t][3] = 0.f;
        }

    const short8v* __restrict__ wbv_hi = (const short8v*)wb;
    const short8v* __restrict__ wbv_lo = (const short8v*)(wb + W2B_ELEMS);

    const int px8 = l15 & 7;
    const int pyb = l15 >> 3;

    for (int tap = 0; tap < 9; ++tap) {
        int ky = tap / 3;
        int kx = tap - ky * 3;
        int rb[4], rs[4];
        #pragma unroll
        for (int mi = 0; mi < 4; ++mi) {
            int row = (mi*2 + pyb + ky)*10 + px8 + kx;
            rb[mi] = row << 6;
            rs[mi] = (row & 7) << 3;
        }
        #pragma unroll
        for (int ks = 0; ks < 2; ++ks) {
            int boff = ((tap*2 + ks)*8 + w*2)*64 + lane;
            short8v bh0 = wbv_hi[boff];
            short8v bh1 = wbv_hi[boff + 64];
            short8v afr[4];
            #pragma unroll
            for (int mi = 0; mi < 4; ++mi) {
                int ch = (((ks << 2) + quad) << 3) ^ rs[mi];
                afr[mi] = *(const short8v*)(s_hid + rb[mi] + ch);   // ds_read_b128, swizzled
            }
            #pragma unroll
            for (int mi = 0; mi < 4; ++mi) {
                acc[mi][0] = __builtin_amdgcn_mfma_f32_16x16x32_bf16(afr[mi], bh0, acc[mi][0], 0, 0, 0);
                acc[mi][1] = __builtin_amdgcn_mfma_f32_16x16x32_bf16(afr[mi], bh1, acc[mi][1], 0, 0, 0);
            }
            short8v bl0 = wbv_lo[boff];
            short8v bl1 = wbv_lo[boff + 64];
            #pragma unroll
            for (int mi = 0; mi < 4; ++mi) {
                acc[mi][0] = __builtin_amdgcn_mfma_f32_16x16x32_bf16(afr[mi], bl0, acc[mi][0], 0, 0, 0);
                acc[mi][1] = __builtin_amdgcn_mfma_f32_16x16x32_bf16(afr[mi], bl1, acc[mi][1], 0, 0, 0);
            }
        }
    }

    // ---------- Epilogue: acc -> p_buf (overwrites A_t/s_hid/s_clean), spline ----------
    float* p_buf = s_un;
    const float* b2c = b2 + w * PPC;      // wave-uniform -> scalar loads

    __syncthreads();   // all s_hid MFMA reads complete before p_buf overwrites
    #pragma unroll
    for (int mi = 0; mi < 4; ++mi) {
        #pragma unroll
        for (int t = 0; t < 2; ++t) {
            int col = (w*2 + t)*16 + l15;
            if (col < NCOLS) {    // cols >=116 are padding; would wrap PSTR (R3 bug)
                f32x4 v = acc[mi][t];
                int base = (mi*16 + quad*4) * PSTR + col;
                p_buf[base]          = v[0];
                p_buf[base + PSTR]   = v[1];
                p_buf[base + 2*PSTR] = v[2];
                p_buf[base + 3*PSTR] = v[3];
            }
        }
    }
    __syncthreads();

    // spline: thread -> (c = w, pixel = lane); all 256 threads active, single pass
    float pv[PPC];
    #pragma unroll
    for (int j = 0; j < PPC; ++j)
        pv[j] = p_buf[lane * PSTR + w * PPC + j];

    const float scale = 0.125f;   // 1/sqrt(HIDDEN)
    float uw[NB], uh[NB], ud9[NB-1];
    #pragma unroll
    for (int j = 0; j < NB; ++j)   uw[j]  = (pv[j]      + b2c[j])      * scale;
    #pragma unroll
    for (int j = 0; j < NB; ++j)   uh[j]  = (pv[NB+j]   + b2c[NB+j])   * scale;
    #pragma unroll
    for (int j = 0; j < NB-1; ++j) ud9[j] =  pv[2*NB+j] + b2c[2*NB+j];

    float mw = uw[0];
    #pragma unroll
    for (int j = 1; j < NB; ++j) mw = fmaxf(mw, uw[j]);
    float sw = 0.0f;
    #pragma unroll
    for (int j = 0; j < NB; ++j) { uw[j] = __expf(uw[j] - mw); sw += uw[j]; }
    float isw = 1.0f / sw;
    float cw[NB+1];
    cw[0] = -TB;
    float run = 0.0f;
    #pragma unroll
    for (int j = 0; j < NB; ++j) {
        float wj = MINW + (1.0f - MINW*NB) * (uw[j] * isw);
        run += wj;
        cw[j+1] = -TB + 2.0f*TB*run;
    }
    cw[NB] = TB;

    float mh = uh[0];
    #pragma unroll
    for (int j = 1; j < NB; ++j) mh = fmaxf(mh, uh[j]);
    float sh = 0.0f;
    #pragma unroll
    for (int j = 0; j < NB; ++j) { uh[j] = __expf(uh[j] - mh); sh += uh[j]; }
    float ish = 1.0f / sh;
    float chh[NB+1];
    chh[0] = -TB;
    float runh = 0.0f;
    #pragma unroll
    for (int j = 0; j < NB; ++j) {
        float hj = MINH + (1.0f - MINH*NB) * (uh[j] * ish);
        runh += hj;
        chh[j+1] = -TB + 2.0f*TB*runh;
    }
    chh[NB] = TB;

    float dv[NB+1];
    dv[0] = 1.0f; dv[NB] = 1.0f;
    #pragma unroll
    for (int k = 0; k < NB-1; ++k) {
        float v = ud9[k];
        // softplus via fast intrinsics: exp(-|v|) tiny -> 1+t rounds to 1 -> log 0,
        // matching the log1p asymptote
        float sp = fmaxf(v, 0.0f) + __logf(1.0f + __expf(-fabsf(v)));
        dv[k+1] = MIND + sp;
    }

    float xin = fminf(fmaxf(xv, -TB), TB);
    int cnt = 0;
    #pragma unroll
    for (int k = 0; k <= NB; ++k) cnt += (xin >= cw[k]) ? 1 : 0;
    int idx = cnt - 1;
    idx = idx < 0 ? 0 : (idx > NB-1 ? NB-1 : idx);

    float icw = cw[0], inw = cw[1], ich = chh[0], inh = chh[1], d0 = dv[0], d1 = dv[1];
    #pragma unroll
    for (int k = 1; k < NB; ++k) {
        bool m = (idx == k);
        icw = m ? cw[k]    : icw;
        inw = m ? cw[k+1]  : inw;
        ich = m ? chh[k]   : ich;
        inh = m ? chh[k+1] : inh;
        d0  = m ? dv[k]    : d0;
        d1  = m ? dv[k+1]  : d1;
    }
    float ibw = inw - icw;
    float ihh = inh - ich;
    float idl = ihh / ibw;
    float th  = (xin - icw) / ibw;
    float omt = 1.0f - th;
    float tt  = th * omt;
    float numer = ihh * (idl*th*th + d0*tt);
    float den   = idl + (d0 + d1 - 2.0f*idl)*tt;
    float z_in  = ich + numer/den;
    float dnum  = idl*idl*(d1*th*th + 2.0f*idl*tt + d0*omt*omt);
    float lad_in = __logf(dnum) - 2.0f*__logf(den);
    bool inside = (xv >= -TB) && (xv <= TB);
    float z = inside ? z_in : xv;
    float lad = inside ? lad_in : 0.0f;
    out[gidx] = z;

    // ---------- block-reduce lad, one atomic per block ----------
    #pragma unroll
    for (int off = 32; off >= 1; off >>= 1)
        lad += __shfl_xor(lad, off, 64);
    if (lane == 0) s_red[w] = lad;
    __syncthreads();
    if (tid == 0)
        atomicAdd(out + ZTOT + b, s_red[0] + s_red[1] + s_red[2] + s_red[3]);
}

extern "C" void kernel_launch(void* const* d_in, const int* in_sizes, int n_in,
                              void* d_out, int out_size, void* d_ws, size_t ws_size,
                              hipStream_t stream) {
    const float* x     = (const float*)d_in[0];
    const float* clean = (const float*)d_in[1];
    const float* W1    = (const float*)d_in[2];
    const float* b1    = (const float*)d_in[3];
    const float* W2    = (const float*)d_in[4];
    const float* b2    = (const float*)d_in[5];
    float* out = (float*)d_out;
    unsigned short* wb = (unsigned short*)d_ws;   // 294912 + 16384 B (W2 hi/lo + W1 hi/lo)

    zero_lad_kernel<<<1, 16, 0, stream>>>(out);
    prepack_w<<<(W2B_ELEMS + W1B_ELEMS + 255)/256, 256, 0, stream>>>(W2, W1, wb);
    fused_kernel<<<BB*32*32, 256, 0, stream>>>(x, clean, b1, b2, wb, out);
}

// Round 10
// 534.317 us; speedup vs baseline: 2.3700x; 1.1946x over previous
//
#include <hip/hip_runtime.h>
#include <math.h>

#define NB 10
#define PPC 29          // 3*NB-1
#define CCH 4
#define HID 64
#define HH 256
#define WW 256
#define BB 16
#define TB 1.0f
#define MINW 0.001f
#define MINH 0.001f
#define MIND 0.001f

#define ZTOT (BB*CCH*HH*WW)     // 4194304

// Tile: 8x8 pixels. M=64, N=128 (116 valid), K=576. 16384 blocks.
#define HALO_PIX 100            // 10 x 10
#define PSTR 117                // p_buf row stride (f32): odd -> conflict-free spline reads
#define NCOLS 116               // valid N columns; >=116 is zero-padding (never stored)
#define W2B_ELEMS (18*8*64*8)   // 73728 bf16 per copy; hi+lo = 294912 B
#define W1B_ELEMS 4096          // per copy: [ks(2)][nt(4)][lane(64)][j(8)]; hi+lo = 16384 B

// LDS word map inside the 64*PSTR f32 union:
//   A_tile  words    0..3583  (112 rows x 32 words, bf16 im2col, swizzled)
//   s_hid   words 3584..6783  (100 rows x 32 words, bf16, swizzled)
//   s_clean words 6784..7359  (4ch x 12 x 12 f32)
//   p_buf   words    0..7487  (epilogue, overwrites all, barrier-ordered)

typedef __attribute__((ext_vector_type(8))) short short8v;
typedef __attribute__((ext_vector_type(4))) float f32x4;

__device__ inline unsigned short f2bf(float f) {
    unsigned u = __float_as_uint(f);
    unsigned r = (u + 0x7FFFu + ((u >> 16) & 1u)) >> 16;
    return (unsigned short)r;
}
__device__ inline float bf2f(unsigned short s) {
    return __uint_as_float(((unsigned)s) << 16);
}

__global__ void zero_lad_kernel(float* out) {
    out[ZTOT + threadIdx.x] = 0.0f;
}

// Prepack W2 (hi/lo) and W1 (hi/lo) into MFMA B-fragment order.
// W2: w2b[copy(2)][kidx(18)][ntile(8)][lane(64)][j(8)]; kidx=tap*2+ks,
//     n=ntile*16+(lane&15), ci=ks*32+(lane>>4)*8+j.
// W1: w1b[copy(2)][ks(2)][nt(4)][lane(64)][j(8)]; co=nt*16+(lane&15),
//     k=ks*32+(lane>>4)*8+j; W1 flat index = co*36+k (k<36), else 0.
__global__ void prepack_w(const float* __restrict__ W2, const float* __restrict__ W1,
                          unsigned short* __restrict__ wb) {
    int idx = blockIdx.x * 256 + threadIdx.x;
    if (idx < W2B_ELEMS) {
        int j    = idx & 7;
        int lane = (idx >> 3) & 63;
        int nt   = (idx >> 9) & 7;
        int kidx = idx >> 12;            // 0..17
        int tap  = kidx >> 1;
        int ks   = kidx & 1;
        int ky   = tap / 3;
        int kx   = tap - ky * 3;
        int n    = nt * 16 + (lane & 15);
        int ci   = ks * 32 + (lane >> 4) * 8 + j;
        float v = 0.0f;
        if (n < PPC * CCH) v = W2[((n * HID + ci) * 3 + ky) * 3 + kx];
        unsigned short hi = f2bf(v);
        wb[idx]             = hi;
        wb[idx + W2B_ELEMS] = f2bf(v - bf2f(hi));
    } else if (idx < W2B_ELEMS + W1B_ELEMS) {
        int e    = idx - W2B_ELEMS;
        int j    = e & 7;
        int lane = (e >> 3) & 63;
        int nt   = (e >> 9) & 3;
        int ks   = (e >> 11) & 1;
        int co   = nt * 16 + (lane & 15);
        int k    = ks * 32 + (lane >> 4) * 8 + j;
        float v = (k < 36) ? W1[co * 36 + k] : 0.0f;
        unsigned short hi = f2bf(v);
        wb[2*W2B_ELEMS + e]             = hi;
        wb[2*W2B_ELEMS + W1B_ELEMS + e] = f2bf(v - bf2f(hi));
    }
}

// (256,4): the (256,5) ~102-VGPR cap spilled this body (R8: 1.75 GB, R9: 1.15 GB
// scratch writes). 128 VGPRs fits peak pressure; 16 waves/CU, LDS 121 KB/CU.
__global__ __launch_bounds__(256, 4)
void fused_kernel(const float* __restrict__ x, const float* __restrict__ clean,
                  const float* __restrict__ b1, const float* __restrict__ b2,
                  const unsigned short* __restrict__ wb, float* __restrict__ out)
{
    __shared__ __align__(16) float s_un[64 * PSTR];   // 29952 B
    __shared__ float s_red[4];

    unsigned short* A_t     = (unsigned short*)s_un;          // 112 x 64 bf16
    unsigned short* s_hid   = (unsigned short*)(s_un + 3584); // 100 x 64 bf16
    float*          s_clean = s_un + 6784;                    // 4 x 12 x 12 f32

    const int tid  = threadIdx.x;
    const int blk  = blockIdx.x;
    const int b    = blk >> 10;
    const int ty   = (blk >> 5) & 31;
    const int tx   = blk & 31;
    const int Y0 = ty * 8, X0 = tx * 8;

    const int w    = tid >> 6;        // wave id == spline channel c == conv1 ntile == conv2 N-quarter
    const int lane = tid & 63;
    const int l15  = lane & 15;
    const int quad = lane >> 4;

    // ---------- Phase A: stage clean tile (4ch x 12 x 12, zero-padded) ----------
    for (int i = tid; i < CCH*12*12; i += 256) {
        int c  = i / 144;
        int r  = i - c * 144;
        int cy = r / 12;
        int cx = r - cy * 12;
        int iy = Y0 - 2 + cy, ix = X0 - 2 + cx;
        float v = 0.0f;
        if (iy >= 0 && iy < HH && ix >= 0 && ix < WW)
            v = clean[((b*CCH + c) << 16) + iy*WW + ix];
        s_clean[i] = v;
    }
    __syncthreads();

    // ---------- Phase A2: build im2col A-tile (112 x 64 bf16, swizzled) ----------
    // A[m][k]: m = halo pixel (10x10 row-major, rows 100..111 are pad),
    //          k = ci*9 + ky*3 + kx for k<36, zero for k>=36.
    for (int i = tid; i < 3584; i += 256) {
        int m  = i >> 5;
        int wd = i & 31;
        int hy = m / 10, hx = m - hy * 10;
        unsigned short h2[2];
        #pragma unroll
        for (int e = 0; e < 2; ++e) {
            int k  = wd*2 + e;
            int kc = (k < 36) ? k : 0;
            int c  = kc / 9;
            int t  = kc - 9*c;
            int ky = t / 3;
            int kx = t - 3*ky;
            float v = s_clean[c*144 + (hy + ky)*12 + (hx + kx)];
            if (k >= 36 || m >= HALO_PIX) v = 0.0f;
            h2[e] = f2bf(v);
        }
        unsigned pk = (unsigned)h2[0] | ((unsigned)h2[1] << 16);
        int chunk = (wd >> 2) ^ (m & 7);
        *(unsigned*)(A_t + (m << 6) + (chunk << 3) + ((wd & 3) << 1)) = pk;
    }
    __syncthreads();

    // ---------- Phase B: conv1 via MFMA. Wave w: co in [16w,16w+16), 7 mtiles ----------
    {
        const short8v* w1v = (const short8v*)(wb + 2*W2B_ELEMS);
        // [copy][ks][nt][lane]
        short8v c1h0 = w1v[(0*4 + w)*64 + lane];          // hi ks0
        short8v c1h1 = w1v[(1*4 + w)*64 + lane];          // hi ks1
        short8v c1l0 = w1v[(2*4 + w)*64 + lane];          // lo ks0
        short8v c1l1 = w1v[(3*4 + w)*64 + lane];          // lo ks1
        float bias = b1[w*16 + l15];

        #pragma unroll
        for (int mt = 0; mt < 7; ++mt) {
            int m  = mt*16 + l15;
            int rb = m << 6;
            int rs = (m & 7) << 3;
            short8v af0 = *(const short8v*)(A_t + rb + ((quad << 3) ^ rs));        // ks0
            short8v af1 = *(const short8v*)(A_t + rb + (((4 + quad) << 3) ^ rs));  // ks1
            f32x4 a;
            a[0] = 0.f; a[1] = 0.f; a[2] = 0.f; a[3] = 0.f;
            a = __builtin_amdgcn_mfma_f32_16x16x32_bf16(af0, c1h0, a, 0, 0, 0);
            a = __builtin_amdgcn_mfma_f32_16x16x32_bf16(af1, c1h1, a, 0, 0, 0);
            a = __builtin_amdgcn_mfma_f32_16x16x32_bf16(af0, c1l0, a, 0, 0, 0);
            a = __builtin_amdgcn_mfma_f32_16x16x32_bf16(af1, c1l1, a, 0, 0, 0);
            // epilogue: hid = valid ? relu(acc + bias) : 0  -> s_hid (swizzled)
            #pragma unroll
            for (int r = 0; r < 4; ++r) {
                int p = mt*16 + quad*4 + r;
                if (p < HALO_PIX) {
                    int hy = p / 10, hx = p - hy*10;
                    int iy = Y0 - 1 + hy, ix = X0 - 1 + hx;
                    bool ok = ((unsigned)iy < HH) && ((unsigned)ix < WW);
                    float v = ok ? fmaxf(a[r] + bias, 0.0f) : 0.0f;
                    int ch = ((w*2 + (l15 >> 3)) ^ (p & 7)) << 3;
                    s_hid[(p << 6) + ch + (l15 & 7)] = f2bf(v);
                }
            }
        }
    }
    __syncthreads();

    // ---------- Phase C: conv2 implicit GEMM via MFMA (B = W2_hi + W2_lo) ----------
    // Wave w: ntiles {2w, 2w+1} x 4 mtiles = 8 acc tiles (32 f32/thread).
    // No B-prefetch (R8 spill lesson).
    f32x4 acc[4][2];
    #pragma unroll
    for (int mi = 0; mi < 4; ++mi)
        #pragma unroll
        for (int t = 0; t < 2; ++t) {
            acc[mi][t][0] = 0.f; acc[mi][t][1] = 0.f;
            acc[mi][t][2] = 0.f; acc[mi][t][3] = 0.f;
        }

    const short8v* __restrict__ wbv_hi = (const short8v*)wb;
    const short8v* __restrict__ wbv_lo = (const short8v*)(wb + W2B_ELEMS);

    const int px8 = l15 & 7;
    const int pyb = l15 >> 3;

    for (int tap = 0; tap < 9; ++tap) {
        int ky = tap / 3;
        int kx = tap - ky * 3;
        int rb[4], rs[4];
        #pragma unroll
        for (int mi = 0; mi < 4; ++mi) {
            int row = (mi*2 + pyb + ky)*10 + px8 + kx;
            rb[mi] = row << 6;
            rs[mi] = (row & 7) << 3;
        }
        #pragma unroll
        for (int ks = 0; ks < 2; ++ks) {
            int boff = ((tap*2 + ks)*8 + w*2)*64 + lane;
            short8v bh0 = wbv_hi[boff];
            short8v bh1 = wbv_hi[boff + 64];
            short8v afr[4];
            #pragma unroll
            for (int mi = 0; mi < 4; ++mi) {
                int ch = (((ks << 2) + quad) << 3) ^ rs[mi];
                afr[mi] = *(const short8v*)(s_hid + rb[mi] + ch);   // ds_read_b128, swizzled
            }
            #pragma unroll
            for (int mi = 0; mi < 4; ++mi) {
                acc[mi][0] = __builtin_amdgcn_mfma_f32_16x16x32_bf16(afr[mi], bh0, acc[mi][0], 0, 0, 0);
                acc[mi][1] = __builtin_amdgcn_mfma_f32_16x16x32_bf16(afr[mi], bh1, acc[mi][1], 0, 0, 0);
            }
            short8v bl0 = wbv_lo[boff];
            short8v bl1 = wbv_lo[boff + 64];
            #pragma unroll
            for (int mi = 0; mi < 4; ++mi) {
                acc[mi][0] = __builtin_amdgcn_mfma_f32_16x16x32_bf16(afr[mi], bl0, acc[mi][0], 0, 0, 0);
                acc[mi][1] = __builtin_amdgcn_mfma_f32_16x16x32_bf16(afr[mi], bl1, acc[mi][1], 0, 0, 0);
            }
        }
    }

    // ---------- Epilogue: acc -> p_buf (overwrites A_t/s_hid/s_clean), spline ----------
    float* p_buf = s_un;
    const float* b2c = b2 + w * PPC;      // wave-uniform -> scalar loads

    __syncthreads();   // all s_hid MFMA reads complete before p_buf overwrites
    #pragma unroll
    for (int mi = 0; mi < 4; ++mi) {
        #pragma unroll
        for (int t = 0; t < 2; ++t) {
            int col = (w*2 + t)*16 + l15;
            if (col < NCOLS) {    // cols >=116 are padding; would wrap PSTR (R3 bug)
                f32x4 v = acc[mi][t];
                int base = (mi*16 + quad*4) * PSTR + col;
                p_buf[base]          = v[0];
                p_buf[base + PSTR]   = v[1];
                p_buf[base + 2*PSTR] = v[2];
                p_buf[base + 3*PSTR] = v[3];
            }
        }
    }
    __syncthreads();

    // x load here (not prefetched at entry): early load anchored 2 regs + long
    // live ranges in both spilling rounds; other resident waves hide the L2 hit.
    const int spy = lane >> 3, spx = lane & 7;
    const int gidx = ((b*CCH + w) << 16) + (Y0 + spy)*WW + (X0 + spx);
    const float xv = x[gidx];

    // spline: thread -> (c = w, pixel = lane); all 256 threads active, single pass
    float pv[PPC];
    #pragma unroll
    for (int j = 0; j < PPC; ++j)
        pv[j] = p_buf[lane * PSTR + w * PPC + j];

    const float scale = 0.125f;   // 1/sqrt(HIDDEN)
    float uw[NB], uh[NB], ud9[NB-1];
    #pragma unroll
    for (int j = 0; j < NB; ++j)   uw[j]  = (pv[j]      + b2c[j])      * scale;
    #pragma unroll
    for (int j = 0; j < NB; ++j)   uh[j]  = (pv[NB+j]   + b2c[NB+j])   * scale;
    #pragma unroll
    for (int j = 0; j < NB-1; ++j) ud9[j] =  pv[2*NB+j] + b2c[2*NB+j];

    float mw = uw[0];
    #pragma unroll
    for (int j = 1; j < NB; ++j) mw = fmaxf(mw, uw[j]);
    float sw = 0.0f;
    #pragma unroll
    for (int j = 0; j < NB; ++j) { uw[j] = __expf(uw[j] - mw); sw += uw[j]; }
    float isw = 1.0f / sw;
    float cw[NB+1];
    cw[0] = -TB;
    float run = 0.0f;
    #pragma unroll
    for (int j = 0; j < NB; ++j) {
        float wj = MINW + (1.0f - MINW*NB) * (uw[j] * isw);
        run += wj;
        cw[j+1] = -TB + 2.0f*TB*run;
    }
    cw[NB] = TB;

    float mh = uh[0];
    #pragma unroll
    for (int j = 1; j < NB; ++j) mh = fmaxf(mh, uh[j]);
    float sh = 0.0f;
    #pragma unroll
    for (int j = 0; j < NB; ++j) { uh[j] = __expf(uh[j] - mh); sh += uh[j]; }
    float ish = 1.0f / sh;
    float chh[NB+1];
    chh[0] = -TB;
    float runh = 0.0f;
    #pragma unroll
    for (int j = 0; j < NB; ++j) {
        float hj = MINH + (1.0f - MINH*NB) * (uh[j] * ish);
        runh += hj;
        chh[j+1] = -TB + 2.0f*TB*runh;
    }
    chh[NB] = TB;

    float dv[NB+1];
    dv[0] = 1.0f; dv[NB] = 1.0f;
    #pragma unroll
    for (int k = 0; k < NB-1; ++k) {
        float v = ud9[k];
        // softplus via fast intrinsics: exp(-|v|) tiny -> 1+t rounds to 1 -> log 0,
        // matching the log1p asymptote
        float sp = fmaxf(v, 0.0f) + __logf(1.0f + __expf(-fabsf(v)));
        dv[k+1] = MIND + sp;
    }

    float xin = fminf(fmaxf(xv, -TB), TB);
    int cnt = 0;
    #pragma unroll
    for (int k = 0; k <= NB; ++k) cnt += (xin >= cw[k]) ? 1 : 0;
    int idx = cnt - 1;
    idx = idx < 0 ? 0 : (idx > NB-1 ? NB-1 : idx);

    float icw = cw[0], inw = cw[1], ich = chh[0], inh = chh[1], d0 = dv[0], d1 = dv[1];
    #pragma unroll
    for (int k = 1; k < NB; ++k) {
        bool m = (idx == k);
        icw = m ? cw[k]    : icw;
        inw = m ? cw[k+1]  : inw;
        ich = m ? chh[k]   : ich;
        inh = m ? chh[k+1] : inh;
        d0  = m ? dv[k]    : d0;
        d1  = m ? dv[k+1]  : d1;
    }
    float ibw = inw - icw;
    float ihh = inh - ich;
    float idl = ihh / ibw;
    float th  = (xin - icw) / ibw;
    float omt = 1.0f - th;
    float tt  = th * omt;
    float numer = ihh * (idl*th*th + d0*tt);
    float den   = idl + (d0 + d1 - 2.0f*idl)*tt;
    float z_in  = ich + numer/den;
    float dnum  = idl*idl*(d1*th*th + 2.0f*idl*tt + d0*omt*omt);
    float lad_in = __logf(dnum) - 2.0f*__logf(den);
    bool inside = (xv >= -TB) && (xv <= TB);
    float z = inside ? z_in : xv;
    float lad = inside ? lad_in : 0.0f;
    out[gidx] = z;

    // ---------- block-reduce lad, one atomic per block ----------
    #pragma unroll
    for (int off = 32; off >= 1; off >>= 1)
        lad += __shfl_xor(lad, off, 64);
    if (lane == 0) s_red[w] = lad;
    __syncthreads();
    if (tid == 0)
        atomicAdd(out + ZTOT + b, s_red[0] + s_red[1] + s_red[2] + s_red[3]);
}

extern "C" void kernel_launch(void* const* d_in, const int* in_sizes, int n_in,
                              void* d_out, int out_size, void* d_ws, size_t ws_size,
                              hipStream_t stream) {
    const float* x     = (const float*)d_in[0];
    const float* clean = (const float*)d_in[1];
    const float* W1    = (const float*)d_in[2];
    const float* b1    = (const float*)d_in[3];
    const float* W2    = (const float*)d_in[4];
    const float* b2    = (const float*)d_in[5];
    float* out = (float*)d_out;
    unsigned short* wb = (unsigned short*)d_ws;   // 294912 + 16384 B (W2 hi/lo + W1 hi/lo)

    zero_lad_kernel<<<1, 16, 0, stream>>>(out);
    prepack_w<<<(W2B_ELEMS + W1B_ELEMS + 255)/256, 256, 0, stream>>>(W2, W1, wb);
    fused_kernel<<<BB*32*32, 256, 0, stream>>>(x, clean, b1, b2, wb, out);
}